// Round 1
// baseline (2272.359 us; speedup 1.0000x reference)
//
#include <hip/hip_runtime.h>
#include <hip/hip_bf16.h>

#define NF 100000
#define NH 49152
#define EDG 400000

// ---------------- helpers ----------------
__device__ __forceinline__ float rdl(float v, int l) {
    return __int_as_float(__builtin_amdgcn_readlane(__float_as_int(v), l));
}
__device__ __forceinline__ float fast_tanh(float x) {
    // tanh(x) = 1 - 2/(e^{2x}+1)  (exact identity; __expf handles overflow -> inf -> 1)
    float ex = __expf(2.0f * x);
    return 1.0f - 2.0f / (ex + 1.0f);
}

// ---------------- degree counting ----------------
__global__ void count_deg(const int* __restrict__ enc_src, const int* __restrict__ enc_dst,
                          const int* __restrict__ dec_src, const int* __restrict__ dec_dst,
                          float* __restrict__ d_se, float* __restrict__ d_de,
                          float* __restrict__ d_sd, float* __restrict__ d_dd) {
    int e = blockIdx.x * 256 + threadIdx.x;
    if (e < EDG) {
        atomicAdd(&d_se[enc_src[e]], 1.0f);
        atomicAdd(&d_de[enc_dst[e]], 1.0f);
        atomicAdd(&d_sd[dec_src[e]], 1.0f);
        atomicAdd(&d_dd[dec_dst[e]], 1.0f);
    }
}

// ---------------- single-block exclusive scan over dec_dst degree -> CSR offsets ----------------
__global__ void scan_kernel(const float* __restrict__ deg, int* __restrict__ offs,
                            int* __restrict__ cursor, int n) {
    __shared__ int wsums[17];
    __shared__ int carry_s;
    const int tid = threadIdx.x;            // 1024
    const int lane = tid & 63, wid = tid >> 6;
    if (tid == 0) carry_s = 0;
    __syncthreads();
    const int nch = (n + 1023) >> 10;
    for (int c = 0; c < nch; ++c) {
        int i = (c << 10) + tid;
        int v = (i < n) ? (int)(deg[i] + 0.5f) : 0;
        int s = v;
        #pragma unroll
        for (int off = 1; off < 64; off <<= 1) {
            int tv = __shfl_up(s, off);
            if (lane >= off) s += tv;
        }
        if (lane == 63) wsums[wid] = s;
        __syncthreads();
        if (tid == 0) {
            int acc = 0;
            #pragma unroll
            for (int w = 0; w < 16; ++w) { int tv = wsums[w]; wsums[w] = acc; acc += tv; }
            wsums[16] = acc;
        }
        __syncthreads();
        int excl = carry_s + wsums[wid] + (s - v);
        if (i < n) { offs[i] = excl; cursor[i] = excl; }
        __syncthreads();
        if (tid == 0) carry_s += wsums[16];
        __syncthreads();
    }
    if (tid == 0) offs[n] = carry_s;
}

// ---------------- in-place deg -> deg^{-1/2} (clamped) ----------------
__global__ void normalize_kernel(float* __restrict__ w, int n) {
    int i = blockIdx.x * 256 + threadIdx.x;
    if (i < n) {
        float d = fmaxf(w[i], 1.0f);
        w[i] = rsqrtf(d);
    }
}

// ---------------- CSR fill (grouped by dec_dst) ----------------
__global__ void csr_fill(const int* __restrict__ dec_src, const int* __restrict__ dec_dst,
                         int* __restrict__ cursor, int* __restrict__ csr) {
    int e = blockIdx.x * 256 + threadIdx.x;
    if (e < EDG) {
        int dst = dec_dst[e];
        int idx = atomicAdd(&cursor[dst], 1);
        csr[idx] = dec_src[e];
    }
}

// ---------------- encoder scatter: agg[dst,ti] += feat[src,ti]*c_se[src] ----------------
__global__ void enc_scatter(const int* __restrict__ enc_src, const int* __restrict__ enc_dst,
                            const float* __restrict__ feat, const float* __restrict__ c_se,
                            float* __restrict__ agg) {
    int gid = blockIdx.x * 256 + threadIdx.x;
    if (gid < EDG * 12) {
        int e = gid / 12;
        int ti = gid - e * 12;
        int src = enc_src[e], dst = enc_dst[e];
        float v = feat[src * 12 + ti];
        v = (v != v) ? 0.0f : v;   // nan_to_num
        atomicAdd(&agg[dst * 12 + ti], v * c_se[src]);
    }
}

// ---------------- precompute u,v (space2 attention collapse) ----------------
__global__ void prep_uv(const float* __restrict__ W_lin, const float* __restrict__ b_lin,
                        const float* __restrict__ W_a1, const float* __restrict__ b_a1,
                        const float* __restrict__ W_o, float* __restrict__ uvs) {
    int k = threadIdx.x;   // 128
    float su = 0.f, sv = 0.f;
    for (int h = 0; h < 64; ++h) {
        su = fmaf(W_lin[h], W_a1[h * 128 + k], su);
        sv = fmaf(b_lin[h], W_a1[h * 128 + k], sv);
    }
    uvs[k] = su;
    uvs[128 + k] = sv + b_a1[k];
    if (k == 0) {
        float a = 0.f, b = 0.f;
        for (int h = 0; h < 64; ++h) {
            a = fmaf(W_lin[h], W_o[h], a);
            b = fmaf(b_lin[h], W_o[h], b);
        }
        uvs[256] = a;  // wlo
        uvs[257] = b;  // blo
    }
}

// ---------------- per-step: m_t[n,h] = relu(h_proc[n,t,h]) * c_sd[n], recomputed from agg ----------------
__global__ void make_m(const float* __restrict__ agg, const float* __restrict__ c_de,
                       const float* __restrict__ c_sd, const float* __restrict__ W_enc,
                       const float* __restrict__ b_enc, const float* __restrict__ W_proc,
                       const float* __restrict__ b_proc, float* __restrict__ m_t, int t) {
    int gid = blockIdx.x * 256 + threadIdx.x;
    if (gid >= NH * 64) return;
    int n = gid >> 6, h = gid & 63;
    float cde = c_de[n];
    float s = 0.f;
    #pragma unroll
    for (int ti = 0; ti < 12; ++ti) {
        float a = agg[n * 12 + ti] * cde;
        float he = fmaf(a, W_enc[ti * 64 + h], b_enc[ti * 64 + h]);
        he = he > 0.f ? he : 0.01f * he;            // leaky_relu
        s = fmaf(he, W_proc[ti * 12 + t], s);
    }
    float hp = s + b_proc[t];
    hp = fmaxf(hp, 0.f);                             // relu
    m_t[gid] = hp * c_sd[n];
}

// ---------------- fused decoder step: gather + GEMV(64x64) + attention + output ----------------
__global__ __launch_bounds__(256) void dec_post_kernel(
    const float* __restrict__ m_t, const int* __restrict__ offs, const int* __restrict__ csr,
    const float* __restrict__ c_dd, const float* __restrict__ feat,
    const float* __restrict__ W_dec, const float* __restrict__ b_dec,
    const float* __restrict__ W_a1, const float* __restrict__ b_a1,
    const float* __restrict__ W_a2, const float* __restrict__ b_a2p,
    const float* __restrict__ W_o, const float* __restrict__ b_op,
    const float* __restrict__ uvs, float* __restrict__ d_out, int t) {
    __shared__ float WtL[4096];
    __shared__ float Wa1L[8192];
    __shared__ float btL[64], woL_s[64];
    __shared__ float ba1L[128], wa2L[128], uL[128], vL[128];

    const int tid = threadIdx.x;
    const float* Wt = W_dec + t * 4096;
    for (int i = tid; i < 4096; i += 256) WtL[i] = Wt[i];
    for (int i = tid; i < 8192; i += 256) Wa1L[i] = W_a1[i];
    if (tid < 64) { btL[tid] = b_dec[t * 64 + tid]; woL_s[tid] = W_o[tid]; }
    if (tid >= 128) {
        int k = tid - 128;
        ba1L[k] = b_a1[k]; wa2L[k] = W_a2[k]; uL[k] = uvs[k]; vL[k] = uvs[128 + k];
    }
    __syncthreads();

    const int lane = tid & 63;
    const int wid = tid >> 6;
    const int n0 = blockIdx.x * 16 + wid * 4;    // 4 nodes per wave

    // ---- gather: z_j[lane] = c_dd[n] * sum_e m_t[src_e, lane] ----
    float z[4];
    #pragma unroll
    for (int j = 0; j < 4; ++j) {
        int n = n0 + j;
        int beg = offs[n], end = offs[n + 1];
        float a0 = 0.f, a1 = 0.f;
        int e = beg;
        for (; e + 1 < end; e += 2) {
            int s0 = csr[e], s1 = csr[e + 1];
            a0 += m_t[s0 * 64 + lane];
            a1 += m_t[s1 * 64 + lane];
        }
        if (e < end) a0 += m_t[csr[e] * 64 + lane];
        z[j] = (a0 + a1) * c_dd[n];
    }

    // ---- GEMV1: space1_j[lane] = leaky(sum_h z_j[h]*W_t[h,lane] + b_t[lane]) ----
    float acc1[4] = {0.f, 0.f, 0.f, 0.f};
    #pragma unroll 16
    for (int h = 0; h < 64; ++h) {
        float w = WtL[h * 64 + lane];
        acc1[0] = fmaf(rdl(z[0], h), w, acc1[0]);
        acc1[1] = fmaf(rdl(z[1], h), w, acc1[1]);
        acc1[2] = fmaf(rdl(z[2], h), w, acc1[2]);
        acc1[3] = fmaf(rdl(z[3], h), w, acc1[3]);
    }
    float sp1[4];
    #pragma unroll
    for (int j = 0; j < 4; ++j) {
        float xx = acc1[j] + btL[lane];
        sp1[j] = xx > 0.f ? xx : 0.01f * xx;
    }

    // ---- GEMV2: hidden_j[k] for k = 2*lane, 2*lane+1 ----
    float h0[4] = {0.f, 0.f, 0.f, 0.f}, h1[4] = {0.f, 0.f, 0.f, 0.f};
    #pragma unroll 16
    for (int h = 0; h < 64; ++h) {
        float2 w2 = *reinterpret_cast<const float2*>(&Wa1L[h * 128 + 2 * lane]);
        #pragma unroll
        for (int j = 0; j < 4; ++j) {
            float s = rdl(sp1[j], h);
            h0[j] = fmaf(s, w2.x, h0[j]);
            h1[j] = fmaf(s, w2.y, h1[j]);
        }
    }

    // ---- y_prev ----
    float yp[4];
    #pragma unroll
    for (int j = 0; j < 4; ++j) {
        int n = n0 + j;
        float v;
        if (t == 0) { v = feat[n * 12 + 11]; v = (v != v) ? 0.f : v; }
        else        { v = d_out[(t - 1) * NF + n]; }
        yp[j] = v;
    }

    const float k0b = ba1L[2 * lane], k1b = ba1L[2 * lane + 1];
    const float wa0 = wa2L[2 * lane], wa1v = wa2L[2 * lane + 1];
    const float u0 = uL[2 * lane], u1 = uL[2 * lane + 1];
    const float v0 = vL[2 * lane], v1 = vL[2 * lane + 1];
    const float wol = woL_s[lane];
    const float wlo = uvs[256], blo = uvs[257];
    const float ba2 = b_a2p[0], bo = b_op[0];

    #pragma unroll
    for (int j = 0; j < 4; ++j) {
        float p1 = fast_tanh(h0[j] + k0b) * wa0 + fast_tanh(h1[j] + k1b) * wa1v;
        float p2 = fast_tanh(fmaf(yp[j], u0, v0)) * wa0 + fast_tanh(fmaf(yp[j], u1, v1)) * wa1v;
        float pw = sp1[j] * wol;
        #pragma unroll
        for (int d = 1; d < 64; d <<= 1) {
            p1 += __shfl_xor(p1, d);
            p2 += __shfl_xor(p2, d);
            pw += __shfl_xor(pw, d);
        }
        float s1s = p1 + ba2, s2s = p2 + ba2;
        float mx = fmaxf(s1s, s2s);
        float e1 = __expf(s1s - mx), e2 = __expf(s2s - mx);
        float inv = 1.0f / (e1 + e2);
        float y = (e1 * pw + e2 * fmaf(wlo, yp[j], blo)) * inv + bo;
        if (lane == 0) d_out[t * NF + n0 + j] = y;
    }
}

// ---------------- launch ----------------
extern "C" void kernel_launch(void* const* d_in, const int* in_sizes, int n_in,
                              void* d_out, int out_size, void* d_ws, size_t ws_size,
                              hipStream_t stream) {
    const float* feat   = (const float*)d_in[0];
    const int* enc_src  = (const int*)d_in[1];
    const int* enc_dst  = (const int*)d_in[2];
    const int* dec_src  = (const int*)d_in[3];
    const int* dec_dst  = (const int*)d_in[4];
    const float* W_enc  = (const float*)d_in[5];
    const float* b_enc  = (const float*)d_in[6];
    const float* W_proc = (const float*)d_in[7];
    const float* b_proc = (const float*)d_in[8];
    const float* W_dec  = (const float*)d_in[9];
    const float* b_dec  = (const float*)d_in[10];
    const float* W_lin  = (const float*)d_in[11];
    const float* b_lin  = (const float*)d_in[12];
    const float* W_a1   = (const float*)d_in[13];
    const float* b_a1   = (const float*)d_in[14];
    const float* W_a2   = (const float*)d_in[15];
    const float* b_a2   = (const float*)d_in[16];
    const float* W_o    = (const float*)d_in[17];
    const float* b_o    = (const float*)d_in[18];
    float* out = (float*)d_out;

    float* W = (float*)d_ws;
    float* deg_se = W;                     // NF      (becomes c_se)
    float* deg_de = W + 100000;            // NH      (becomes c_de)
    float* deg_sd = W + 149152;            // NH      (becomes c_sd)
    float* deg_dd = W + 198304;            // NF      (becomes c_dd)
    float* agg    = W + 298304;            // NH*12
    float* m_t    = W + 888128;            // NH*64
    float* uvs    = W + 4033856;           // 260
    int*   offs   = (int*)(W + 4034120);   // NF+1
    int*   cursor = offs + 100001;         // NF
    int*   csr    = cursor + 100000;       // EDG

    // zero degree arrays + agg
    hipMemsetAsync(W, 0, (size_t)888128 * 4, stream);

    count_deg<<<(EDG + 255) / 256, 256, 0, stream>>>(enc_src, enc_dst, dec_src, dec_dst,
                                                     deg_se, deg_de, deg_sd, deg_dd);
    scan_kernel<<<1, 1024, 0, stream>>>(deg_dd, offs, cursor, NF);
    normalize_kernel<<<(298304 + 255) / 256, 256, 0, stream>>>(W, 298304);
    csr_fill<<<(EDG + 255) / 256, 256, 0, stream>>>(dec_src, dec_dst, cursor, csr);
    enc_scatter<<<(EDG * 12 + 255) / 256, 256, 0, stream>>>(enc_src, enc_dst, feat, deg_se, agg);
    prep_uv<<<1, 128, 0, stream>>>(W_lin, b_lin, W_a1, b_a1, W_o, uvs);

    for (int t = 0; t < 12; ++t) {
        make_m<<<(NH * 64) / 256, 256, 0, stream>>>(agg, deg_de, deg_sd, W_enc, b_enc,
                                                    W_proc, b_proc, m_t, t);
        dec_post_kernel<<<NF / 16, 256, 0, stream>>>(m_t, offs, csr, deg_dd, feat,
                                                     W_dec, b_dec, W_a1, b_a1, W_a2, b_a2,
                                                     W_o, b_o, uvs, out, t);
    }
}

// Round 2
// 1277.788 us; speedup vs baseline: 1.7784x; 1.7784x over previous
//
#include <hip/hip_runtime.h>
#include <hip/hip_bf16.h>

#define NF 100000
#define NH 49152
#define EDG 400000

typedef __attribute__((ext_vector_type(8))) short short8;
typedef __attribute__((ext_vector_type(4))) float float4v;
typedef unsigned short u16;
typedef unsigned int u32;

__device__ __forceinline__ float b2f(u16 b) { return __uint_as_float(((u32)b) << 16); }
__device__ __forceinline__ u16 f2b(float x) {
    u32 u = __float_as_uint(x);
    u32 r = u + 0x7FFFu + ((u >> 16) & 1u);
    return (u16)(r >> 16);
}
__device__ __forceinline__ float fast_tanh(float x) {
    float ex = __expf(2.0f * x);
    return 1.0f - 2.0f / (ex + 1.0f);
}

// ---------------- degree counting ----------------
__global__ void count_deg(const int* __restrict__ enc_src, const int* __restrict__ enc_dst,
                          const int* __restrict__ dec_src, const int* __restrict__ dec_dst,
                          float* __restrict__ d_se, float* __restrict__ d_de,
                          float* __restrict__ d_sd, float* __restrict__ d_dd) {
    int e = blockIdx.x * 256 + threadIdx.x;
    if (e < EDG) {
        atomicAdd(&d_se[enc_src[e]], 1.0f);
        atomicAdd(&d_de[enc_dst[e]], 1.0f);
        atomicAdd(&d_sd[dec_src[e]], 1.0f);
        atomicAdd(&d_dd[dec_dst[e]], 1.0f);
    }
}

// ---------------- single-block exclusive scan over dec_dst degree -> CSR offsets ----------------
__global__ void scan_kernel(const float* __restrict__ deg, int* __restrict__ offs,
                            int* __restrict__ cursor, int n) {
    __shared__ int wsums[17];
    __shared__ int carry_s;
    const int tid = threadIdx.x;            // 1024
    const int lane = tid & 63, wid = tid >> 6;
    if (tid == 0) carry_s = 0;
    __syncthreads();
    const int nch = (n + 1023) >> 10;
    for (int c = 0; c < nch; ++c) {
        int i = (c << 10) + tid;
        int v = (i < n) ? (int)(deg[i] + 0.5f) : 0;
        int s = v;
        #pragma unroll
        for (int off = 1; off < 64; off <<= 1) {
            int tv = __shfl_up(s, off);
            if (lane >= off) s += tv;
        }
        if (lane == 63) wsums[wid] = s;
        __syncthreads();
        if (tid == 0) {
            int acc = 0;
            #pragma unroll
            for (int w = 0; w < 16; ++w) { int tv = wsums[w]; wsums[w] = acc; acc += tv; }
            wsums[16] = acc;
        }
        __syncthreads();
        int excl = carry_s + wsums[wid] + (s - v);
        if (i < n) { offs[i] = excl; cursor[i] = excl; }
        __syncthreads();
        if (tid == 0) carry_s += wsums[16];
        __syncthreads();
    }
    if (tid == 0) offs[n] = carry_s;
}

__global__ void normalize_kernel(float* __restrict__ w, int n) {
    int i = blockIdx.x * 256 + threadIdx.x;
    if (i < n) {
        float d = fmaxf(w[i], 1.0f);
        w[i] = rsqrtf(d);
    }
}

__global__ void csr_fill(const int* __restrict__ dec_src, const int* __restrict__ dec_dst,
                         int* __restrict__ cursor, int* __restrict__ csr) {
    int e = blockIdx.x * 256 + threadIdx.x;
    if (e < EDG) {
        int dst = dec_dst[e];
        int idx = atomicAdd(&cursor[dst], 1);
        csr[idx] = dec_src[e];
    }
}

__global__ void enc_scatter(const int* __restrict__ enc_src, const int* __restrict__ enc_dst,
                            const float* __restrict__ feat, const float* __restrict__ c_se,
                            float* __restrict__ agg) {
    int gid = blockIdx.x * 256 + threadIdx.x;
    if (gid < EDG * 12) {
        int e = gid / 12;
        int ti = gid - e * 12;
        int src = enc_src[e], dst = enc_dst[e];
        float v = feat[src * 12 + ti];
        v = (v != v) ? 0.0f : v;
        atomicAdd(&agg[dst * 12 + ti], v * c_se[src]);
    }
}

__global__ void prep_uv(const float* __restrict__ W_lin, const float* __restrict__ b_lin,
                        const float* __restrict__ W_a1, const float* __restrict__ b_a1,
                        const float* __restrict__ W_o, float* __restrict__ uvs) {
    int k = threadIdx.x;   // 128
    float su = 0.f, sv = 0.f;
    for (int h = 0; h < 64; ++h) {
        su = fmaf(W_lin[h], W_a1[h * 128 + k], su);
        sv = fmaf(b_lin[h], W_a1[h * 128 + k], sv);
    }
    uvs[k] = su;
    uvs[128 + k] = sv + b_a1[k];
    if (k == 0) {
        float a = 0.f, b = 0.f;
        for (int h = 0; h < 64; ++h) {
            a = fmaf(W_lin[h], W_o[h], a);
            b = fmaf(b_lin[h], W_o[h], b);
        }
        uvs[256] = a;  // wlo
        uvs[257] = b;  // blo
    }
}

// ---------------- bf16 B-fragment prep for MFMA (layout: B[k=quad*8+j+32*kc][n=c*16+(lane&15)]) ----------------
__global__ void prep_frag(const float* __restrict__ W_dec, const float* __restrict__ W_a1,
                          u16* __restrict__ fragWdec, u16* __restrict__ fragWa1) {
    int gid = blockIdx.x * 256 + threadIdx.x;    // 7168 total
    if (gid >= 7168) return;
    int L = gid & 63;
    int f = gid >> 6;          // 0..95: W_dec (t=f>>3, fr=f&7); 96..111: W_a1
    int q = L >> 4, cb = L & 15;
    if (f < 96) {
        int fr = f & 7;
        int c = fr >> 1, kc = fr & 1;
        int k0 = kc * 32 + q * 8;
        int n = c * 16 + cb;
        int t = f >> 3;
        #pragma unroll
        for (int j = 0; j < 8; ++j)
            fragWdec[(f * 64 + L) * 8 + j] = f2b(W_dec[t * 4096 + (k0 + j) * 64 + n]);
    } else {
        int fr = f - 96;
        int c2 = fr >> 1, kc = fr & 1;
        int k0 = kc * 32 + q * 8;
        int n = c2 * 16 + cb;
        #pragma unroll
        for (int j = 0; j < 8; ++j)
            fragWa1[(fr * 64 + L) * 8 + j] = f2b(W_a1[(k0 + j) * 128 + n]);
    }
}

// ---------------- m for all steps: m[t][n][h] = relu(h_proc)*c_sd, bf16 ----------------
__global__ void make_all(const float* __restrict__ agg, const float* __restrict__ c_de,
                         const float* __restrict__ c_sd, const float* __restrict__ W_enc,
                         const float* __restrict__ b_enc, const float* __restrict__ W_proc,
                         const float* __restrict__ b_proc, u16* __restrict__ m_base,
                         int t0, int t1) {
    int gid = blockIdx.x * 256 + threadIdx.x;
    if (gid >= NH * 64) return;
    int n = gid >> 6, h = gid & 63;
    float cde = c_de[n], csd = c_sd[n];
    float he[12];
    #pragma unroll
    for (int ti = 0; ti < 12; ++ti) {
        float a = agg[n * 12 + ti] * cde;
        float x = fmaf(a, W_enc[ti * 64 + h], b_enc[ti * 64 + h]);
        he[ti] = x > 0.f ? x : 0.01f * x;
    }
    for (int t = t0; t < t1; ++t) {
        float s = b_proc[t];
        #pragma unroll
        for (int ti = 0; ti < 12; ++ti) s = fmaf(he[ti], W_proc[ti * 12 + t], s);
        s = fmaxf(s, 0.f) * csd;
        m_base[(size_t)(t - t0) * (NH * 64) + gid] = f2b(s);
    }
}

// ---------------- fused decoder step: gather + MFMA GEMMs + attention ----------------
// block = 4 waves, 16 nodes/wave, 64 nodes/block
__global__ __launch_bounds__(256) void dec_mfma(
    const u16* __restrict__ m_bf, const int* __restrict__ offs, const int* __restrict__ csr,
    const float* __restrict__ c_dd, const float* __restrict__ feat,
    const u16* __restrict__ fragWdec, const u16* __restrict__ fragWa1,
    const float* __restrict__ b_dec, const float* __restrict__ b_a1,
    const float* __restrict__ W_a2, const float* __restrict__ b_a2p,
    const float* __restrict__ W_o, const float* __restrict__ b_op,
    const float* __restrict__ uvs, float* __restrict__ d_out, int t) {
    __shared__ __align__(16) u16 fragL[12288];  // 8 frags W_t (4096) + 16 frags W_a1 (8192)
    __shared__ __align__(16) u16 zs[5632];      // 4 waves x 16 rows x 88 (pad: 176B stride, 16B aligned, 2-way banks)
    __shared__ float yps[64];

    const int tid = threadIdx.x, lane = tid & 63, wid = tid >> 6;
    const int nb = blockIdx.x * 64;

    const uint4* gsrc1 = (const uint4*)(fragWdec + (size_t)t * 4096);
    const uint4* gsrc2 = (const uint4*)fragWa1;
    uint4* dl = (uint4*)fragL;
    for (int i = tid; i < 512; i += 256) dl[i] = gsrc1[i];
    for (int i = tid; i < 1024; i += 256) dl[512 + i] = gsrc2[i];
    if (tid < 64) {
        int n = nb + tid; float v = 0.f;
        if (n < NF) {
            if (t == 0) { v = feat[n * 12 + 11]; v = (v != v) ? 0.f : v; }
            else        { v = d_out[(size_t)(t - 1) * NF + n]; }
        }
        yps[tid] = v;
    }
    __syncthreads();

    u16* zw = zs + wid * 1408;
    const int nw = nb + wid * 16;

    // ---- gather z (wave-uniform edge loop; scalar csr loads) ----
    for (int j = 0; j < 16; ++j) {
        int n = nw + j;
        float acc = 0.f;
        if (n < NF) {
            int beg = offs[n], end = offs[n + 1];
            float a0 = 0.f, a1 = 0.f;
            int e = beg;
            for (; e + 1 < end; e += 2) {
                int q0 = csr[e], q1 = csr[e + 1];
                a0 += b2f(m_bf[(size_t)q0 * 64 + lane]);
                a1 += b2f(m_bf[(size_t)q1 * 64 + lane]);
            }
            if (e < end) a0 += b2f(m_bf[(size_t)csr[e] * 64 + lane]);
            acc = (a0 + a1) * c_dd[n];
        }
        zw[j * 88 + lane] = f2b(acc);
    }

    const int colb = lane & 15, aq = lane >> 4;
    const u16* ab = zw + colb * 88 + aq * 8;
    short8 a0 = *(const short8*)ab;            // A[m=colb][k=aq*8+j]
    short8 a1 = *(const short8*)(ab + 32);     // k += 32

    // ---- GEMM1: space1[16 nodes][64] ----
    float4v C1[4];
    #pragma unroll
    for (int c = 0; c < 4; ++c) {
        float4v z4 = {0.f, 0.f, 0.f, 0.f};
        short8 b0 = *(const short8*)(fragL + (c * 2 + 0) * 512 + lane * 8);
        short8 b1 = *(const short8*)(fragL + (c * 2 + 1) * 512 + lane * 8);
        z4 = __builtin_amdgcn_mfma_f32_16x16x32_bf16(a0, b0, z4, 0, 0, 0);
        C1[c] = __builtin_amdgcn_mfma_f32_16x16x32_bf16(a1, b1, z4, 0, 0, 0);
    }

    // ---- epilogue1: bias + leaky, pw partial, write sp (A-layout for GEMM2) ----
    float pw[4] = {0.f, 0.f, 0.f, 0.f};
    #pragma unroll
    for (int c = 0; c < 4; ++c) {
        float bt = b_dec[t * 64 + c * 16 + colb];
        float wo = W_o[c * 16 + colb];
        #pragma unroll
        for (int r = 0; r < 4; ++r) {
            float xx = C1[c][r] + bt;            // C: row(node)=aq*4+r, col=c*16+colb
            float sp = xx > 0.f ? xx : 0.01f * xx;
            pw[r] = fmaf(sp, wo, pw[r]);
            zw[(aq * 4 + r) * 88 + c * 16 + colb] = f2b(sp);
        }
    }

    short8 sa0 = *(const short8*)ab;
    short8 sa1 = *(const short8*)(ab + 32);

    // ---- GEMM2: hidden[16 nodes][128] ----
    float4v C2[8];
    #pragma unroll
    for (int c = 0; c < 8; ++c) {
        float4v z4 = {0.f, 0.f, 0.f, 0.f};
        short8 b0 = *(const short8*)(fragL + 4096 + (c * 2 + 0) * 512 + lane * 8);
        short8 b1 = *(const short8*)(fragL + 4096 + (c * 2 + 1) * 512 + lane * 8);
        z4 = __builtin_amdgcn_mfma_f32_16x16x32_bf16(sa0, b0, z4, 0, 0, 0);
        C2[c] = __builtin_amdgcn_mfma_f32_16x16x32_bf16(sa1, b1, z4, 0, 0, 0);
    }

    float ypr[4];
    #pragma unroll
    for (int r = 0; r < 4; ++r) ypr[r] = yps[wid * 16 + aq * 4 + r];

    // ---- epilogue2: tanh-attention partials ----
    float p1[4] = {0.f, 0.f, 0.f, 0.f}, p2[4] = {0.f, 0.f, 0.f, 0.f};
    #pragma unroll
    for (int c = 0; c < 8; ++c) {
        int k = c * 16 + colb;
        float ba = b_a1[k], wa = W_a2[k], uu = uvs[k], vv = uvs[128 + k];
        #pragma unroll
        for (int r = 0; r < 4; ++r) {
            p1[r] = fmaf(fast_tanh(C2[c][r] + ba), wa, p1[r]);
            p2[r] = fmaf(fast_tanh(fmaf(ypr[r], uu, vv)), wa, p2[r]);
        }
    }

    // ---- reduce over the 16-lane quad group ----
    #pragma unroll
    for (int m = 1; m < 16; m <<= 1) {
        #pragma unroll
        for (int r = 0; r < 4; ++r) {
            p1[r] += __shfl_xor(p1[r], m);
            p2[r] += __shfl_xor(p2[r], m);
            pw[r] += __shfl_xor(pw[r], m);
        }
    }

    if (colb == 0) {
        float wlo = uvs[256], blo = uvs[257], ba2 = b_a2p[0], bo = b_op[0];
        #pragma unroll
        for (int r = 0; r < 4; ++r) {
            int n = nw + aq * 4 + r;
            if (n < NF) {
                float s1s = p1[r] + ba2, s2s = p2[r] + ba2;
                float mx = fmaxf(s1s, s2s);
                float e1 = __expf(s1s - mx), e2 = __expf(s2s - mx);
                float inv = 1.f / (e1 + e2);
                d_out[(size_t)t * NF + n] = (e1 * pw[r] + e2 * fmaf(wlo, ypr[r], blo)) * inv + bo;
            }
        }
    }
}

// ---------------- launch ----------------
extern "C" void kernel_launch(void* const* d_in, const int* in_sizes, int n_in,
                              void* d_out, int out_size, void* d_ws, size_t ws_size,
                              hipStream_t stream) {
    const float* feat   = (const float*)d_in[0];
    const int* enc_src  = (const int*)d_in[1];
    const int* enc_dst  = (const int*)d_in[2];
    const int* dec_src  = (const int*)d_in[3];
    const int* dec_dst  = (const int*)d_in[4];
    const float* W_enc  = (const float*)d_in[5];
    const float* b_enc  = (const float*)d_in[6];
    const float* W_proc = (const float*)d_in[7];
    const float* b_proc = (const float*)d_in[8];
    const float* W_dec  = (const float*)d_in[9];
    const float* b_dec  = (const float*)d_in[10];
    const float* W_lin  = (const float*)d_in[11];
    const float* b_lin  = (const float*)d_in[12];
    const float* W_a1   = (const float*)d_in[13];
    const float* b_a1   = (const float*)d_in[14];
    const float* W_a2   = (const float*)d_in[15];
    const float* b_a2   = (const float*)d_in[16];
    const float* W_o    = (const float*)d_in[17];
    const float* b_o    = (const float*)d_in[18];
    float* out = (float*)d_out;

    float* W = (float*)d_ws;
    float* deg_se = W;                       // NF      (-> c_se)
    float* deg_de = W + 100000;              // NH      (-> c_de)
    float* deg_sd = W + 149152;              // NH      (-> c_sd)
    float* deg_dd = W + 198304;              // NF      (-> c_dd)
    float* agg    = W + 298304;              // NH*12   end 888128
    float* uvs    = W + 888128;              // 260     (pad to 888448)
    int*   offs   = (int*)(W + 888448);      // NF+1
    int*   cursor = offs + 100001;           // NF
    int*   csr    = cursor + 100000;         // EDG     end 1488449 -> pad 1488512
    u16*   fragWdec = (u16*)(W + 1488512);   // 49152 u16 = 24576 floats
    u16*   fragWa1  = (u16*)(W + 1513088);   // 8192 u16 = 4096 floats
    u16*   m_all    = (u16*)(W + 1517184);   // full: 12*NH*64 u16; fallback: NH*64 u16

    const size_t need_full = (size_t)(1517184 + 18874368) * 4;   // ~81.6 MB
    const bool full = ws_size >= need_full;

    hipMemsetAsync(W, 0, (size_t)888448 * 4, stream);

    count_deg<<<(EDG + 255) / 256, 256, 0, stream>>>(enc_src, enc_dst, dec_src, dec_dst,
                                                     deg_se, deg_de, deg_sd, deg_dd);
    scan_kernel<<<1, 1024, 0, stream>>>(deg_dd, offs, cursor, NF);
    normalize_kernel<<<(298304 + 255) / 256, 256, 0, stream>>>(W, 298304);
    csr_fill<<<(EDG + 255) / 256, 256, 0, stream>>>(dec_src, dec_dst, cursor, csr);
    enc_scatter<<<(EDG * 12 + 255) / 256, 256, 0, stream>>>(enc_src, enc_dst, feat, deg_se, agg);
    prep_uv<<<1, 128, 0, stream>>>(W_lin, b_lin, W_a1, b_a1, W_o, uvs);
    prep_frag<<<28, 256, 0, stream>>>(W_dec, W_a1, fragWdec, fragWa1);

    const int dec_grid = (NF + 63) / 64;
    if (full) {
        make_all<<<(NH * 64) / 256, 256, 0, stream>>>(agg, deg_de, deg_sd, W_enc, b_enc,
                                                      W_proc, b_proc, m_all, 0, 12);
        for (int t = 0; t < 12; ++t) {
            dec_mfma<<<dec_grid, 256, 0, stream>>>(m_all + (size_t)t * NH * 64, offs, csr,
                                                   deg_dd, feat, fragWdec, fragWa1,
                                                   b_dec, b_a1, W_a2, b_a2, W_o, b_o,
                                                   uvs, out, t);
        }
    } else {
        for (int t = 0; t < 12; ++t) {
            make_all<<<(NH * 64) / 256, 256, 0, stream>>>(agg, deg_de, deg_sd, W_enc, b_enc,
                                                          W_proc, b_proc, m_all, t, t + 1);
            dec_mfma<<<dec_grid, 256, 0, stream>>>(m_all, offs, csr,
                                                   deg_dd, feat, fragWdec, fragWa1,
                                                   b_dec, b_a1, W_a2, b_a2, W_o, b_o,
                                                   uvs, out, t);
        }
    }
}